// Round 8
// baseline (11.893 us; speedup 1.0000x reference)
//
#include <hip/hip_runtime.h>

// StealNMSLoss on MI355X.
//
// Mathematical simplification (verified rounds 1-7, absmax 0.0): the four
// angle masks partition [0,180) and angle always lies in [0,180), so
// sum_c mask_c == 1 per pixel. Therefore
//   loss = -sum(log_norm) / (B*4*H*W)
// and the Sobel/angle pipeline on true_labels cancels entirely.
// log_norm = log(clip(ep/resp, 1e-6, 1)), ep = exp(p/0.1),
// resp = vertical 5-tap sum of ep (reflect pad) + 1e-6.
// ep/resp < 1 always, so the upper clip is inert:
//   log_norm = max(10*p_c - log(resp), ln 1e-6)
// Base-2 form (v_exp_f32 / v_log_f32 are natively base-2):
//   u = p*(10*log2 e);  log_norm = ln2 * max(u_c - log2(sum 2^u + 1e-6), log2 1e-6)
//
// Structure history:
//   r4: main + tiny reduce (2 dispatches)            -> 14.75us
//   r5: cooperative grid.sync                        -> 107us  (grid sync ~50us on 8 XCDs)
//   r6: 1 dispatch + release/acquire slot handshake  -> 18.6us (cross-XCD polling >> 2nd dispatch)
//   r7: r4 + full register prefetch (20-deep MLP)    -> 11.57us (best)
// r8: occupancy 16 -> 32 waves/CU. RPB=8 (12-row prefetch, ~60 VGPR),
//     __launch_bounds__(256,8) caps VGPR at 64 -> 8 blocks/CU. Halo amp rises
//     to 1.5x but halo rows are same-XCD L2 hits (XCD-chunked swizzle), so HBM
//     fetch is ~flat. Reduce kernel: single wave, no LDS.

#if defined(__has_builtin) && __has_builtin(__builtin_amdgcn_exp2f) && __has_builtin(__builtin_amdgcn_logf)
#define EXP2(x) __builtin_amdgcn_exp2f(x)
#define LOG2(x) __builtin_amdgcn_logf(x)
#else
#define EXP2(x) __expf((x) * 0.693147180559945f)
#define LOG2(x) (__logf(x) * 1.4426950408889634f)
#endif

#define HH 1024
#define WW 1024
#define NB 8
#define RPB 8                  // rows per strip -> 128 strips
#define TPB 256                // threads/block; each thread owns 2 columns
#define CT 2                   // column tiles (1024 / (256*2))
#define STRIPS (HH / RPB)      // 128
#define NBLK (NB * STRIPS * CT)   // 2048 blocks = 8 blocks/CU
#define SC 14.4269504088896f      // 10 * log2(e)
#define L2EPS (-19.9315685693242f)   // log2(1e-6)

__global__ __launch_bounds__(TPB, 8) void nms_main_kernel(const float* __restrict__ pred,
                                                          float* __restrict__ part) {
    const int tx = threadIdx.x;
    const int bp = blockIdx.x;
    // XCD-chunked bijective swizzle (2048 % 8 == 0): each XCD owns one batch image.
    const int bx = ((bp & 7) << 8) + (bp >> 3);   // [batch(8) | strip(128) | coltile(2)]
    const int ct = bx & 1;
    const int ys = (bx >> 1) & (STRIPS - 1);
    const int b  = bx >> 8;
    const int y0 = ys * RPB;
    const float* img = pred + ((size_t)b << 20) + (ct * (TPB * 2)) + (tx * 2);

    // reflect row index (np.pad 'reflect': -1 -> 1, H -> H-2)
    auto ld = [&](int y) -> float2 {
        int r = y < 0 ? -y : (y >= HH ? 2 * (HH - 1) - y : y);
        return *reinterpret_cast<const float2*>(img + ((size_t)r << 10));
    };

    // full register prefetch: 12 independent loads in flight per thread
    float2 v[RPB + 4];
#pragma unroll
    for (int i = 0; i < RPB + 4; ++i) v[i] = ld(y0 + i - 2);

    float ex[RPB + 4], ey[RPB + 4];
#pragma unroll
    for (int i = 0; i < RPB + 4; ++i) {
        v[i].x *= SC; v[i].y *= SC;          // u = p * 10*log2(e)
        ex[i] = EXP2(v[i].x);
        ey[i] = EXP2(v[i].y);
    }

    float accx = 0.0f, accy = 0.0f;
#pragma unroll
    for (int i = 0; i < RPB; ++i) {
        float rx = ((ex[i] + ex[i + 1]) + (ex[i + 2] + ex[i + 3])) + (ex[i + 4] + 1e-6f);
        float ry = ((ey[i] + ey[i + 1]) + (ey[i + 2] + ey[i + 3])) + (ey[i + 4] + 1e-6f);
        accx += fmaxf(v[i + 2].x - LOG2(rx), L2EPS);
        accy += fmaxf(v[i + 2].y - LOG2(ry), L2EPS);
    }
    float acc = accx + accy;

    // wave-64 reduction
#pragma unroll
    for (int off = 32; off > 0; off >>= 1)
        acc += __shfl_down(acc, off, 64);

    __shared__ float wsum[TPB / 64];
    if ((tx & 63) == 0) wsum[tx >> 6] = acc;
    __syncthreads();
    if (tx == 0)
        part[bx] = wsum[0] + wsum[1] + wsum[2] + wsum[3];   // plain store, no atomics
}

__global__ __launch_bounds__(64) void nms_reduce_kernel(const float* __restrict__ part,
                                                        float* __restrict__ out) {
    const int tx = threadIdx.x;   // single wave, no LDS, fixed-order sum
    float a = 0.0f;
#pragma unroll
    for (int j = 0; j < NBLK / (64 * 4); ++j) {   // 8 float4 per lane
        float4 vv = reinterpret_cast<const float4*>(part)[tx + j * 64];
        a += (vv.x + vv.y) + (vv.z + vv.w);
    }
#pragma unroll
    for (int off = 32; off > 0; off >>= 1)
        a += __shfl_down(a, off, 64);
    if (tx == 0) {
        // * ln2 (base-2 -> natural), / (B*4*H*W), negated
        out[0] = a * (-0.693147180559945f / 33554432.0f);
    }
}

extern "C" void kernel_launch(void* const* d_in, const int* in_sizes, int n_in,
                              void* d_out, int out_size, void* d_ws, size_t ws_size,
                              hipStream_t stream) {
    const float* pred = (const float*)d_in[0];   // pred_labels [8,1,1024,1024] f32
    // d_in[1] (true_labels) is mathematically unused — masks sum to 1.
    float* part = (float*)d_ws;                  // 2048 block partials
    float* out  = (float*)d_out;
    nms_main_kernel<<<NBLK, TPB, 0, stream>>>(pred, part);
    nms_reduce_kernel<<<1, 64, 0, stream>>>(part, out);
}

// Round 9
// 11.804 us; speedup vs baseline: 1.0075x; 1.0075x over previous
//
#include <hip/hip_runtime.h>

// StealNMSLoss on MI355X.
//
// Mathematical simplification (verified rounds 1-8, absmax 0.0): the four
// angle masks partition [0,180) and angle always lies in [0,180), so
// sum_c mask_c == 1 per pixel. Therefore
//   loss = -sum(log_norm) / (B*4*H*W)
// and the Sobel/angle pipeline on true_labels cancels entirely.
// log_norm = log(clip(ep/resp, 1e-6, 1)), ep = exp(p/0.1),
// resp = vertical 5-tap sum of ep (reflect pad) + 1e-6.
// ep/resp < 1 always, so the upper clip is inert:
//   log_norm = max(10*p_c - log(resp), ln 1e-6)
// Base-2 form (v_exp_f32 / v_log_f32 are natively base-2):
//   u = p*(10*log2 e);  log_norm = ln2 * max(u_c - log2(sum 2^u + 1e-6), log2 1e-6)
//
// Structure history:
//   r4: main + tiny reduce (2 dispatches)            -> 14.75us
//   r5: cooperative grid.sync                        -> 107us  (grid sync ~50us on 8 XCDs)
//   r6: 1 dispatch + release/acquire slot handshake  -> 18.6us (cross-XCD polling >> 2nd dispatch)
//   r7: r4 + full register prefetch (20-deep MLP)    -> 11.57us (best)
//   r8: 32 waves/CU (RPB=8, float2)                  -> 11.89us (occupancy lever neutral ->
//       not latency-bound; halo L2-hits ~free)
// r9: attack VMEM issue rate: float4 loads (16B/lane, G13 sweet spot), RPB=8,
//     CT=1 -> 2x fewer load instrs than r8 at same footprint. v[] reused to
//     hold u after exp to keep VGPR <= 128 (16 waves/CU).

#if defined(__has_builtin) && __has_builtin(__builtin_amdgcn_exp2f) && __has_builtin(__builtin_amdgcn_logf)
#define EXP2(x) __builtin_amdgcn_exp2f(x)
#define LOG2(x) __builtin_amdgcn_logf(x)
#else
#define EXP2(x) __expf((x) * 0.693147180559945f)
#define LOG2(x) (__logf(x) * 1.4426950408889634f)
#endif

#define HH 1024
#define WW 1024
#define NB 8
#define RPB 8                  // rows per strip -> 128 strips
#define TPB 256                // threads/block; each thread owns 4 columns (full width)
#define STRIPS (HH / RPB)      // 128
#define NBLK (NB * STRIPS)     // 1024 blocks = 4 blocks/CU
#define SC 14.4269504088896f   // 10 * log2(e)
#define L2EPS (-19.9315685693242f)   // log2(1e-6)

__global__ __launch_bounds__(TPB, 4) void nms_main_kernel(const float* __restrict__ pred,
                                                          float* __restrict__ part) {
    const int tx = threadIdx.x;
    const int bp = blockIdx.x;
    // XCD-chunked bijective swizzle (1024 % 8 == 0): each XCD owns one batch image.
    const int bx = ((bp & 7) << 7) + (bp >> 3);   // [batch(8) | strip(128)]
    const int ys = bx & (STRIPS - 1);
    const int b  = bx >> 7;
    const int y0 = ys * RPB;
    const float* img = pred + ((size_t)b << 20) + (tx * 4);

    // reflect row index (np.pad 'reflect': -1 -> 1, H -> H-2)
    auto ld = [&](int y) -> float4 {
        int r = y < 0 ? -y : (y >= HH ? 2 * (HH - 1) - y : y);
        return *reinterpret_cast<const float4*>(img + ((size_t)r << 10));
    };

    // full register prefetch: 12 independent dwordx4 loads in flight per thread
    float4 v[RPB + 4];
#pragma unroll
    for (int i = 0; i < RPB + 4; ++i) v[i] = ld(y0 + i - 2);

    // e = exp2(u); v[] is reused to hold u = p * 10*log2(e) (centers needed later)
    float ex[RPB + 4], ey[RPB + 4], ez[RPB + 4], ew[RPB + 4];
#pragma unroll
    for (int i = 0; i < RPB + 4; ++i) {
        v[i].x *= SC; v[i].y *= SC; v[i].z *= SC; v[i].w *= SC;
        ex[i] = EXP2(v[i].x);
        ey[i] = EXP2(v[i].y);
        ez[i] = EXP2(v[i].z);
        ew[i] = EXP2(v[i].w);
    }

    float accx = 0.0f, accy = 0.0f, accz = 0.0f, accw = 0.0f;
#pragma unroll
    for (int i = 0; i < RPB; ++i) {
        float rx = ((ex[i] + ex[i + 1]) + (ex[i + 2] + ex[i + 3])) + (ex[i + 4] + 1e-6f);
        float ry = ((ey[i] + ey[i + 1]) + (ey[i + 2] + ey[i + 3])) + (ey[i + 4] + 1e-6f);
        float rz = ((ez[i] + ez[i + 1]) + (ez[i + 2] + ez[i + 3])) + (ez[i + 4] + 1e-6f);
        float rw = ((ew[i] + ew[i + 1]) + (ew[i + 2] + ew[i + 3])) + (ew[i + 4] + 1e-6f);
        accx += fmaxf(v[i + 2].x - LOG2(rx), L2EPS);
        accy += fmaxf(v[i + 2].y - LOG2(ry), L2EPS);
        accz += fmaxf(v[i + 2].z - LOG2(rz), L2EPS);
        accw += fmaxf(v[i + 2].w - LOG2(rw), L2EPS);
    }
    float acc = (accx + accy) + (accz + accw);

    // wave-64 reduction
#pragma unroll
    for (int off = 32; off > 0; off >>= 1)
        acc += __shfl_down(acc, off, 64);

    __shared__ float wsum[TPB / 64];
    if ((tx & 63) == 0) wsum[tx >> 6] = acc;
    __syncthreads();
    if (tx == 0)
        part[bx] = wsum[0] + wsum[1] + wsum[2] + wsum[3];   // plain store, no atomics
}

__global__ __launch_bounds__(64) void nms_reduce_kernel(const float* __restrict__ part,
                                                        float* __restrict__ out) {
    const int tx = threadIdx.x;   // single wave, no LDS, fixed-order sum
    float a = 0.0f;
#pragma unroll
    for (int j = 0; j < NBLK / (64 * 4); ++j) {   // 4 float4 per lane
        float4 vv = reinterpret_cast<const float4*>(part)[tx + j * 64];
        a += (vv.x + vv.y) + (vv.z + vv.w);
    }
#pragma unroll
    for (int off = 32; off > 0; off >>= 1)
        a += __shfl_down(a, off, 64);
    if (tx == 0) {
        // * ln2 (base-2 -> natural), / (B*4*H*W), negated
        out[0] = a * (-0.693147180559945f / 33554432.0f);
    }
}

extern "C" void kernel_launch(void* const* d_in, const int* in_sizes, int n_in,
                              void* d_out, int out_size, void* d_ws, size_t ws_size,
                              hipStream_t stream) {
    const float* pred = (const float*)d_in[0];   // pred_labels [8,1,1024,1024] f32
    // d_in[1] (true_labels) is mathematically unused — masks sum to 1.
    float* part = (float*)d_ws;                  // 1024 block partials
    float* out  = (float*)d_out;
    nms_main_kernel<<<NBLK, TPB, 0, stream>>>(pred, part);
    nms_reduce_kernel<<<1, 64, 0, stream>>>(part, out);
}